// Round 4
// baseline (471.045 us; speedup 1.0000x reference)
//
#include <hip/hip_runtime.h>
#include <cstdint>

// Problem constants
#define BB 16
#define NN 512
#define CC 768
#define HH 12
#define DD 64
#define HID 3072

typedef __bf16 bf16;
typedef __bf16 bf16x4 __attribute__((ext_vector_type(4)));
typedef __bf16 bf16x8 __attribute__((ext_vector_type(8)));
typedef float f32x4 __attribute__((ext_vector_type(4)));

__device__ __forceinline__ f32x4 mfma16(bf16x8 a, bf16x8 b, f32x4 c) {
    return __builtin_amdgcn_mfma_f32_16x16x32_bf16(a, b, c, 0, 0, 0);
}

__device__ __forceinline__ void g2l16(const bf16* g, bf16* l) {
    __builtin_amdgcn_global_load_lds(
        (const __attribute__((address_space(1))) void*)g,
        (__attribute__((address_space(3))) void*)l, 16, 0, 0);
}

template<int N>
__device__ __forceinline__ void wait_vm() {
    asm volatile("s_waitcnt vmcnt(%0)" :: "n"(N) : "memory");
}

// ---------------- fp32->bf16 cast of one or two tensors into contiguous dst ----------------
__global__ __launch_bounds__(256) void cast2_kernel(
    const float* __restrict__ a, int na4, const float* __restrict__ b, bf16* __restrict__ dst)
{
    int i = blockIdx.x * 256 + threadIdx.x;   // grid sized exactly
    const float* s = (i < na4) ? a : b;
    int off = (i < na4) ? i : i - na4;
    f32x4 v = ((const f32x4*)s)[off];
    bf16x4 o;
    #pragma unroll
    for (int e = 0; e < 4; e++) o[e] = (bf16)v[e];
    ((bf16x4*)dst)[i] = o;
}

// ---------------- LN1: one wave per token ----------------
__global__ __launch_bounds__(256) void ln_kernel(
    const float* __restrict__ in, bf16* __restrict__ out,
    const float* __restrict__ g, const float* __restrict__ bt)
{
    int w = threadIdx.x >> 6, lane = threadIdx.x & 63;
    long t = blockIdx.x * 4 + w;
    const float* xr = in + t * CC;
    float vals[12];
    float s = 0.f, sq = 0.f;
    #pragma unroll
    for (int i = 0; i < 3; i++) {
        int off = lane * 4 + i * 256;
        f32x4 v4 = *(const f32x4*)&xr[off];
        #pragma unroll
        for (int e = 0; e < 4; e++) {
            vals[i * 4 + e] = v4[e];
            s += v4[e]; sq += v4[e] * v4[e];
        }
    }
    #pragma unroll
    for (int m = 1; m < 64; m <<= 1) { s += __shfl_xor(s, m); sq += __shfl_xor(sq, m); }
    float mean = s * (1.f / 768.f);
    float var  = sq * (1.f / 768.f) - mean * mean;
    float rstd = rsqrtf(var + 1e-5f);
    bf16* orow = out + t * CC;
    #pragma unroll
    for (int i = 0; i < 3; i++) {
        int off = lane * 4 + i * 256;
        bf16x4 ov;
        #pragma unroll
        for (int e = 0; e < 4; e++)
            ov[e] = (bf16)((vals[i * 4 + e] - mean) * rstd * g[off + e] + bt[off + e]);
        *(bf16x4*)&orow[off] = ov;
    }
}

// ---------------- LN2 unified (both halves) + x1 += g2*fc2_bias writeback ----------------
__global__ __launch_bounds__(256) void ln2_kernel(
    float* x1, bf16* __restrict__ h2,
    const float* __restrict__ gt, const float* __restrict__ btt,
    const float* __restrict__ gf, const float* __restrict__ btf,
    const float* __restrict__ g2, const float* __restrict__ b2t, const float* __restrict__ b2f)
{
    int w = threadIdx.x >> 6, lane = threadIdx.x & 63;
    long u = blockIdx.x * 4 + w;      // token 0..8191
    int b = (int)(u >> 9), n = (int)(u & 511);
    bool th = n < 256;
    const float* g  = th ? gt : gf;
    const float* bt = th ? btt : btf;
    const float* b2 = th ? b2t : b2f;
    long h2row = th ? ((long)b * 256 + n) : (4096 + (long)b * 256 + (n - 256));
    float* xr = x1 + u * CC;
    float vals[12];
    float s = 0.f, sq = 0.f;
    #pragma unroll
    for (int i = 0; i < 3; i++) {
        int off = lane * 4 + i * 256;
        f32x4 v4 = *(const f32x4*)&xr[off];
        #pragma unroll
        for (int e = 0; e < 4; e++) {
            vals[i * 4 + e] = v4[e];
            s += v4[e]; sq += v4[e] * v4[e];
        }
    }
    #pragma unroll
    for (int m = 1; m < 64; m <<= 1) { s += __shfl_xor(s, m); sq += __shfl_xor(sq, m); }
    float mean = s * (1.f / 768.f);
    float var  = sq * (1.f / 768.f) - mean * mean;
    float rstd = rsqrtf(var + 1e-5f);
    bf16* orow = h2 + h2row * CC;
    #pragma unroll
    for (int i = 0; i < 3; i++) {
        int off = lane * 4 + i * 256;
        bf16x4 ov;
        f32x4 wv;
        #pragma unroll
        for (int e = 0; e < 4; e++) {
            ov[e] = (bf16)((vals[i * 4 + e] - mean) * rstd * g[off + e] + bt[off + e]);
            wv[e] = vals[i * 4 + e] + g2[off + e] * b2[off + e];
        }
        *(bf16x4*)&orow[off] = ov;
        *(f32x4*)&xr[off] = wv;
    }
}

// ---------------- bias precompute, pre-arranged into MFMA C-fragment layout ----------------
// layout: element ((((h*8 + g)*4 + w)*8 + ch)*64 + lane)*16 + (ii*4 + t)
//   == bias[h][row = g*64 + w*16 + (lane>>4)*4 + ii][col = ch*64 + t*16 + (lane&15)]
__global__ __launch_bounds__(256) void bias_kernel(
    const int* __restrict__ rpi, const float* __restrict__ table, bf16* __restrict__ bb)
{
    int flat = blockIdx.x * 256 + threadIdx.x;   // 196608 threads
    int lane = flat & 63;
    int ch   = (flat >> 6) & 7;
    int w    = (flat >> 9) & 3;
    int g    = (flat >> 11) & 7;
    int h    = flat >> 14;
    int row0 = g * 64 + w * 16 + (lane >> 4) * 4;
    int col0 = ch * 64 + (lane & 15);
    bf16x8 v0, v1;
    #pragma unroll
    for (int ii = 0; ii < 4; ii++) {
        #pragma unroll
        for (int t = 0; t < 4; t++) {
            int r = rpi[(row0 + ii) * NN + col0 + t * 16];
            bf16 val = (bf16)table[r * HH + h];
            if (ii < 2) v0[ii * 4 + t] = val;
            else        v1[(ii - 2) * 4 + t] = val;
        }
    }
    bf16* dst = bb + (long)flat * 16;
    *(bf16x8*)dst = v0;
    *(bf16x8*)(dst + 8) = v1;
}

// ------- BMxBN MFMA GEMM, DEPTH-deep LDS ring + ping-pong frag regs: C = A @ Bt^T -------
// Per iter (one barrier): [lgkm0][vm counted][barrier] stage tile t+D | ds_read frags[t+1]
// | MFMA frags[t].  ds-read latency hides under the MFMA cluster; loads stay in flight
// across barriers (vmcnt never drained in the loop). Tail kept uniform by redundantly
// re-staging the final tile (same bytes -> benign).
enum { MODE_QKV = 0, MODE_PROJ = 1, MODE_GELU = 2, MODE_OUT = 3 };

template<int MODE, int K, int KCHUNK, int BM, int BN, int DEPTH>
__global__ __launch_bounds__(256, 3) void gemm_bt(
    const bf16* __restrict__ A, const bf16* __restrict__ Btb,
    const float* __restrict__ cbias, const float* residf,
    const float* __restrict__ gamma,
    bf16* __restrict__ outb0, bf16* __restrict__ outb1, bf16* __restrict__ outb2,
    float* outf, int rowbase)
{
    constexpr int AR = BM / 64;    // staging rounds (256 threads x 16B covers 64 rows x 32 cols)
    constexpr int BR = BN / 64;
    constexpr int L  = AR + BR;    // vmem loads per tile per thread
    constexpr int VMP = (DEPTH - 1) * L;   // prologue wait: tile 0 landed
    constexpr int VM2 = (DEPTH - 2) * L;   // steady state: tile t+1 landed
    constexpr int NT  = KCHUNK / 32;
    static_assert((NT & 1) == 0 && NT > DEPTH + 1, "");
    constexpr int FM = BM / 32;    // frags per wave (m)
    constexpr int FN = BN / 32;
    __shared__ bf16 lsA[DEPTH][BM * 32];
    __shared__ bf16 lsB[DEPTH][BN * 32];
    int tid = threadIdx.x;
    int lane = tid & 63, w = tid >> 6;
    int wm = w & 1, wn = w >> 1;
    // XCD-aware bijective swizzle (nwg % 8 == 0 for every launch in this file)
    int gx = gridDim.x;
    int nwg = gx * gridDim.y;
    int flat = blockIdx.y * gx + blockIdx.x;
    int cpx = nwg >> 3;
    flat = (flat & 7) * cpx + (flat >> 3);
    int bx = flat % gx, by = flat / gx;
    long m0 = (long)by * BM;
    long n0 = (long)bx * BN;
    long kb = (long)blockIdx.z * KCHUNK;
    f32x4 acc[FM][FN] = {};
    const bf16* Ab = A + m0 * K + kb;
    const bf16* Bb = Btb + n0 * K + kb;
    int r0 = tid >> 2, kg0 = (tid & 3) * 8;   // 8 bf16 = 16B per lane
    int la = lane & 15, hk = (lane >> 4) * 8;

    // prologue: stage tiles 0..DEPTH-1 (no waits), then pre-read frags[0]
    #pragma unroll
    for (int d = 0; d < DEPTH; d++) {
        #pragma unroll
        for (int rr = 0; rr < AR; rr++)
            g2l16(Ab + (long)(r0 + rr * 64) * K + d * 32 + kg0, lsA[d] + (tid + rr * 256) * 8);
        #pragma unroll
        for (int rr = 0; rr < BR; rr++)
            g2l16(Bb + (long)(r0 + rr * 64) * K + d * 32 + kg0, lsB[d] + (tid + rr * 256) * 8);
    }
    wait_vm<VMP>();
    __builtin_amdgcn_sched_barrier(0);
    __builtin_amdgcn_s_barrier();
    __builtin_amdgcn_sched_barrier(0);
    bf16x8 afA[FM], bfA[FN], afB[FM], bfB[FN];
    #pragma unroll
    for (int mi = 0; mi < FM; mi++) afA[mi] = *(bf16x8*)&lsA[0][(wm * (BM / 2) + mi * 16 + la) * 32 + hk];
    #pragma unroll
    for (int ni = 0; ni < FN; ni++) bfA[ni] = *(bf16x8*)&lsB[0][(wn * (BN / 2) + ni * 16 + la) * 32 + hk];

    int pc = 0, pn = 1;   // pc = buffer of tile t (dead after this iter's barrier), pn = buffer of tile t+1

#define GEMM_ITER(T, CA, CB, NA, NB)                                                          \
    {                                                                                         \
        asm volatile("s_waitcnt lgkmcnt(0)" ::: "memory");   /* frags[T] in regs (WAR-safe) */\
        __builtin_amdgcn_sched_barrier(0);                                                    \
        wait_vm<VM2>();                                      /* tile T+1 landed (mine) */     \
        __builtin_amdgcn_sched_barrier(0);                                                    \
        __builtin_amdgcn_s_barrier();                        /* everyone: reads done+landed */\
        __builtin_amdgcn_sched_barrier(0);                                                    \
        int st_ = (T) + DEPTH; if (st_ > NT - 1) st_ = NT - 1;                                \
        long sk_ = (long)st_ * 32;                                                            \
        _Pragma("unroll")                                                                     \
        for (int rr = 0; rr < AR; rr++)                                                       \
            g2l16(Ab + (long)(r0 + rr * 64) * K + sk_ + kg0, lsA[pc] + (tid + rr * 256) * 8); \
        _Pragma("unroll")                                                                     \
        for (int rr = 0; rr < BR; rr++)                                                       \
            g2l16(Bb + (long)(r0 + rr * 64) * K + sk_ + kg0, lsB[pc] + (tid + rr * 256) * 8); \
        _Pragma("unroll")                                                                     \
        for (int mi = 0; mi < FM; mi++) NA[mi] = *(bf16x8*)&lsA[pn][(wm * (BM / 2) + mi * 16 + la) * 32 + hk]; \
        _Pragma("unroll")                                                                     \
        for (int ni = 0; ni < FN; ni++) NB[ni] = *(bf16x8*)&lsB[pn][(wn * (BN / 2) + ni * 16 + la) * 32 + hk]; \
        __builtin_amdgcn_s_setprio(1);                                                        \
        _Pragma("unroll")                                                                     \
        for (int mi = 0; mi < FM; mi++)                                                       \
            _Pragma("unroll")                                                                 \
            for (int ni = 0; ni < FN; ni++)                                                   \
                acc[mi][ni] = mfma16(CA[mi], CB[ni], acc[mi][ni]);                            \
        __builtin_amdgcn_s_setprio(0);                                                        \
        pc = pn; pn = (pn + 1 == DEPTH) ? 0 : pn + 1;                                         \
    }

    GEMM_ITER(0, afA, bfA, afB, bfB)
    for (int t = 1; t < NT - 1; t += 2) {
        GEMM_ITER(t, afB, bfB, afA, bfA)
        GEMM_ITER(t + 1, afA, bfA, afB, bfB)
    }
    // final tile NT-1: frags already in B set
    asm volatile("s_waitcnt lgkmcnt(0)" ::: "memory");
    __builtin_amdgcn_sched_barrier(0);
    __builtin_amdgcn_s_setprio(1);
    #pragma unroll
    for (int mi = 0; mi < FM; mi++)
        #pragma unroll
        for (int ni = 0; ni < FN; ni++)
            acc[mi][ni] = mfma16(afB[mi], bfB[ni], acc[mi][ni]);
    __builtin_amdgcn_s_setprio(0);
#undef GEMM_ITER

    int q4 = (lane >> 4) * 4;
    // QKV: the whole block maps into exactly one of q/k/v (768 % BN == 0)
    int sblk = 0, cb0 = 0;
    if constexpr (MODE == MODE_QKV) {
        sblk = (int)(n0 / CC);
        cb0  = (int)n0 - sblk * CC;
    }
    #pragma unroll
    for (int mi = 0; mi < FM; mi++) {
        #pragma unroll
        for (int ni = 0; ni < FN; ni++) {
            long rb = m0 + wm * (BM / 2) + mi * 16 + q4;
            long c  = n0 + wn * (BN / 2) + ni * 16 + la;
            #pragma unroll
            for (int i = 0; i < 4; i++) {
                long r = rb + i;
                float v = acc[mi][ni][i];
                if (MODE == MODE_QKV) {
                    int rem = cb0 + wn * (BN / 2) + ni * 16 + la;
                    int hh = rem >> 6, d = rem & 63;
                    long b = r >> 9, n = r & 511;
                    long dst = (((b * HH + hh) << 9) + n) * 64 + d;
                    if (sblk == 0)      outb0[dst] = (bf16)(v * 0.125f);
                    else if (sblk == 1) outb1[dst] = (bf16)v;
                    else                outb2[dst] = (bf16)v;
                } else if (MODE == MODE_PROJ) {
                    float val = v + cbias[c];
                    long idx = r * CC + c;
                    outf[idx] = residf[idx] + gamma[c] * val;
                } else if (MODE == MODE_GELU) {
                    float val = v + cbias[c];
                    float gl = 0.5f * val * (1.f + erff(val * 0.70710678118f));
                    outb0[r * (long)HID + c] = (bf16)gl;
                } else {  // MODE_OUT: bias pre-added by ln2 writeback; split-K atomic accumulate
                    long grow = (r >> 8) * NN + (r & 255) + rowbase;
                    atomicAdd(outf + grow * CC + c, gamma[c] * v);
                }
            }
        }
    }
}

// ---------------- Flash attention: 128 q-rows per block (two 16-row tiles per wave) ----------------
// grid = b(16) x qt(4) x h(12).  K/V staged once per chunk, reused by both q-sets.
// bias read as 2x16B coalesced loads from pre-arranged fragment layout.
// row-sum l accumulated via mfma(P, ones) (rides the MFMA pipe; no sum-shuffles).
__global__ __launch_bounds__(256, 3) void attn_kernel(
    const bf16* __restrict__ q, const bf16* __restrict__ k, const bf16* __restrict__ v,
    const bf16* __restrict__ bb, bf16* __restrict__ o)
{
    __shared__ bf16 lsK[64 * 72];
    __shared__ bf16 lsVT[64 * 68];
    __shared__ bf16 lsP[4][2][16 * 76];
    int tid = threadIdx.x, lane = tid & 63, w = tid >> 6;
    int b  = blockIdx.x & 15;
    int qt = (blockIdx.x >> 4) & 3;
    int h  = blockIdx.x >> 6;
    long base = (long)(b * HH + h) * NN * DD;
    int la = lane & 15, hi = lane >> 4;
    int qr0 = qt * 128 + w * 16;           // set A rows; set B = +64
    // bias base for (h, granule=qt*2, w); granule stride = 4*8*1024 = 32768
    const bf16* bb0 = bb + ((long)((h * 8 + qt * 2) * 4 + w) * 8) * 1024 + lane * 16;

    bf16x8 qA0 = *(const bf16x8*)&q[base + (long)(qr0 + la) * 64 + hi * 8];
    bf16x8 qA1 = *(const bf16x8*)&q[base + (long)(qr0 + la) * 64 + 32 + hi * 8];
    bf16x8 qB0 = *(const bf16x8*)&q[base + (long)(qr0 + 64 + la) * 64 + hi * 8];
    bf16x8 qB1 = *(const bf16x8*)&q[base + (long)(qr0 + 64 + la) * 64 + 32 + hi * 8];
    f32x4 ofA[4] = {}, ofB[4] = {};
    f32x4 lfA = {}, lfB = {};
    float mA[4], mB[4];
    #pragma unroll
    for (int i = 0; i < 4; i++) { mA[i] = -1e30f; mB[i] = -1e30f; }
    bf16x8 ones;
    #pragma unroll
    for (int e = 0; e < 8; e++) ones[e] = (bf16)1.0f;

    int jr = tid >> 2, dg16 = (tid & 3) * 16;
    for (int ch = 0; ch < 8; ch++) {
        int j0 = ch * 64;
        const bf16* krow = &k[base + (long)(j0 + jr) * 64 + dg16];
        *(bf16x8*)&lsK[jr * 72 + dg16]     = *(const bf16x8*)krow;
        *(bf16x8*)&lsK[jr * 72 + dg16 + 8] = *(const bf16x8*)(krow + 8);
        const bf16* vrow = &v[base + (long)(j0 + jr) * 64 + dg16];
        bf16x8 v0 = *(const bf16x8*)vrow;
        bf16x8 v1 = *(const bf16x8*)(vrow + 8);
        #pragma unroll
        for (int e = 0; e < 8; e++) {
            lsVT[(dg16 + e) * 68 + jr]     = v0[e];
            lsVT[(dg16 + 8 + e) * 68 + jr] = v1[e];
        }
        __syncthreads();

        // QK^T, K-frags shared by both q-sets
        f32x4 sA[4] = {}, sB[4] = {};
        #pragma unroll
        for (int t = 0; t < 4; t++) {
            bf16x8 kf0 = *(bf16x8*)&lsK[(t * 16 + la) * 72 + hi * 8];
            bf16x8 kf1 = *(bf16x8*)&lsK[(t * 16 + la) * 72 + 32 + hi * 8];
            sA[t] = mfma16(qA0, kf0, sA[t]);
            sA[t] = mfma16(qA1, kf1, sA[t]);
            sB[t] = mfma16(qB0, kf0, sB[t]);
            sB[t] = mfma16(qB1, kf1, sB[t]);
        }
        // bias: 2x16B coalesced loads per set
        {
            const bf16* bpA = bb0 + ch * 1024;
            const bf16* bpB = bpA + 32768;
            bf16x8 a0 = *(const bf16x8*)bpA, a1 = *(const bf16x8*)(bpA + 8);
            bf16x8 c0 = *(const bf16x8*)bpB, c1 = *(const bf16x8*)(bpB + 8);
            #pragma unroll
            for (int t = 0; t < 4; t++) {
                sA[t][0] += (float)a0[t];     sA[t][1] += (float)a0[4 + t];
                sA[t][2] += (float)a1[t];     sA[t][3] += (float)a1[4 + t];
                sB[t][0] += (float)c0[t];     sB[t][1] += (float)c0[4 + t];
                sB[t][2] += (float)c1[t];     sB[t][3] += (float)c1[4 + t];
            }
        }
        // online softmax (max-reduce via shuffles; sum deferred to mfma(P, ones))
        #define SM_SET(S, M, OF, LF, PSET)                                               \
        {                                                                                \
            float alpha[4];                                                              \
            _Pragma("unroll")                                                            \
            for (int i = 0; i < 4; i++) {                                                \
                float mx = fmaxf(fmaxf(S[0][i], S[1][i]), fmaxf(S[2][i], S[3][i]));      \
                _Pragma("unroll")                                                        \
                for (int msk = 1; msk < 16; msk <<= 1) mx = fmaxf(mx, __shfl_xor(mx, msk)); \
                float mn = fmaxf(M[i], mx);                                              \
                alpha[i] = __expf(M[i] - mn);                                            \
                M[i] = mn;                                                               \
                _Pragma("unroll")                                                        \
                for (int t = 0; t < 4; t++) S[t][i] = __expf(S[t][i] - mn);              \
            }                                                                            \
            _Pragma("unroll")                                                            \
            for (int t = 0; t < 4; t++) {                                                \
                _Pragma("unroll")                                                        \
                for (int i = 0; i < 4; i++) OF[t][i] *= alpha[i];                        \
            }                                                                            \
            _Pragma("unroll")                                                            \
            for (int i = 0; i < 4; i++) LF[i] *= alpha[i];                               \
            _Pragma("unroll")                                                            \
            for (int i = 0; i < 4; i++) {                                                \
                _Pragma("unroll")                                                        \
                for (int t = 0; t < 4; t++)                                              \
                    lsP[w][PSET][(hi * 4 + i) * 76 + t * 16 + la] = (bf16)S[t][i];       \
            }                                                                            \
        }
        SM_SET(sA, mA, ofA, lfA, 0)
        SM_SET(sB, mB, ofB, lfB, 1)
        #undef SM_SET

        bf16x8 pA0 = *(bf16x8*)&lsP[w][0][la * 76 + hi * 8];
        bf16x8 pA1 = *(bf16x8*)&lsP[w][0][la * 76 + 32 + hi * 8];
        bf16x8 pB0 = *(bf16x8*)&lsP[w][1][la * 76 + hi * 8];
        bf16x8 pB1 = *(bf16x8*)&lsP[w][1][la * 76 + 32 + hi * 8];
        #pragma unroll
        for (int t = 0; t < 4; t++) {
            bf16x8 vf0 = *(bf16x8*)&lsVT[(t * 16 + la) * 68 + hi * 8];
            bf16x8 vf1 = *(bf16x8*)&lsVT[(t * 16 + la) * 68 + 32 + hi * 8];
            ofA[t] = mfma16(pA0, vf0, ofA[t]);
            ofA[t] = mfma16(pA1, vf1, ofA[t]);
            ofB[t] = mfma16(pB0, vf0, ofB[t]);
            ofB[t] = mfma16(pB1, vf1, ofB[t]);
        }
        lfA = mfma16(pA0, ones, lfA);
        lfA = mfma16(pA1, ones, lfA);
        lfB = mfma16(pB0, ones, lfB);
        lfB = mfma16(pB1, ones, lfB);
        __syncthreads();
    }
    float invA[4], invB[4];
    #pragma unroll
    for (int i = 0; i < 4; i++) { invA[i] = 1.f / lfA[i]; invB[i] = 1.f / lfB[i]; }
    #pragma unroll
    for (int t = 0; t < 4; t++) {
        #pragma unroll
        for (int i = 0; i < 4; i++) {
            long rowA = (long)b * NN + qr0 + hi * 4 + i;
            o[rowA * CC + h * 64 + t * 16 + la]        = (bf16)(ofA[t][i] * invA[i]);
            o[(rowA + 64) * CC + h * 64 + t * 16 + la] = (bf16)(ofB[t][i] * invB[i]);
        }
    }
}

extern "C" void kernel_launch(void* const* d_in, const int* in_sizes, int n_in,
                              void* d_out, int out_size, void* d_ws, size_t ws_size,
                              hipStream_t stream)
{
    const float* x     = (const float*)d_in[0];
    const int*   rpi   = (const int*)d_in[2];
    const float* Wqkv  = (const float*)d_in[3];
    const float* Wproj = (const float*)d_in[4];
    const float* bproj = (const float*)d_in[5];
    const float* rtab  = (const float*)d_in[6];
    const float* ln1g  = (const float*)d_in[7];
    const float* ln1b  = (const float*)d_in[8];
    const float* g1    = (const float*)d_in[9];
    const float* g2    = (const float*)d_in[10];
    const float* ln2tg = (const float*)d_in[11];
    const float* ln2tb = (const float*)d_in[12];
    const float* f1tW  = (const float*)d_in[13];
    const float* f1tb  = (const float*)d_in[14];
    const float* f2tW  = (const float*)d_in[15];
    const float* f2tb  = (const float*)d_in[16];
    const float* ln2fg = (const float*)d_in[17];
    const float* ln2fb = (const float*)d_in[18];
    const float* f1fW  = (const float*)d_in[19];
    const float* f1fb  = (const float*)d_in[20];
    const float* f2fW  = (const float*)d_in[21];
    const float* f2fb  = (const float*)d_in[22];
    float* out = (float*)d_out;

    // ws: 4 regions x 12.58MB bf16 = 50.33MB.
    //  rA: q  -> Wproj(bf16) -> h2        rB: k -> hg lo     rC: v -> hg hi
    //  rD: Wqkv(bf16) -> o -> MLP weight pairs (w1,w2 bf16)
    // d_out: h (bf16 LN1) -> bias table (bf16) -> x1 (fp32 residual/result)
    char* ws = (char*)d_ws;
    const long TOKC = (long)BB * NN * CC;        // 6291456
    const int  NFC  = HID * CC;                  // 2359296
    bf16* rA = (bf16*)ws;
    bf16* rB = rA + TOKC;
    bf16* rC = rB + TOKC;
    bf16* rD = rC + TOKC;

    bf16 *qb = rA, *kb = rB, *vb = rC, *o = rD;
    bf16  *h    = (bf16*)d_out;
    bf16  *bbt  = (bf16*)d_out;
    float *x1   = out;
    bf16  *wqkv = rD;     // before o
    bf16  *wpro = rA;     // after q dies
    bf16  *h2   = rA;     // after Wproj dies
    bf16  *hg   = rB;     // spans rB+rC
    bf16  *w1   = rD;     // after o dies
    bf16  *w2   = rD + NFC;

    // 0a. cast Wqkv -> bf16 (rD; o not yet written)
    cast2_kernel<<<1728, 256, 0, stream>>>(Wqkv, 442368, nullptr, wqkv);
    // 1. LN1: fp32 x -> bf16 h (d_out)
    ln_kernel<<<2048, 256, 0, stream>>>(x, h, ln1g, ln1b);
    // 2. QKV projection
    {
        dim3 g(2304 / 128, 8192 / 128, 1);
        gemm_bt<MODE_QKV, 768, 768, 128, 128, 3><<<g, 256, 0, stream>>>(h, wqkv, nullptr, nullptr, nullptr, qb, kb, vb, nullptr, 0);
    }
    // 3. bias table in fragment layout (h dead)
    bias_kernel<<<768, 256, 0, stream>>>(rpi, rtab, bbt);
    // 4. attention (reads rA,rB,rC,bbt; writes o=rD; wqkv dead)
    attn_kernel<<<BB * 4 * HH, 256, 0, stream>>>(qb, kb, vb, bbt, o);
    // 5a. cast Wproj -> bf16 (rA; q dead)
    cast2_kernel<<<576, 256, 0, stream>>>(Wproj, 147456, nullptr, wpro);
    // 5b. proj + residual -> x1 (overwrites d_out; bbt dead); 64x128 tile -> 768 blocks (3/CU)
    {
        dim3 g(768 / 128, 8192 / 64, 1);
        gemm_bt<MODE_PROJ, 768, 768, 64, 128, 4><<<g, 256, 0, stream>>>(o, wpro, bproj, x, g1, nullptr, nullptr, nullptr, x1, 0);
    }
    // 6. LN2 both halves -> h2 (rA; Wproj dead), x1 += g2*fc2_bias
    ln2_kernel<<<2048, 256, 0, stream>>>(x1, h2, ln2tg, ln2tb, ln2fg, ln2fb, g2, f2tb, f2fb);
    // 7. MLP t-half: cast weights (rD; o dead), GELU, OUT split-K=2 with 64x128 tile (3/CU)
    cast2_kernel<<<4608, 256, 0, stream>>>(f1tW, NFC / 4, f2tW, w1);
    {
        dim3 ga(3072 / 128, 4096 / 128, 1);
        gemm_bt<MODE_GELU, 768, 768, 128, 128, 3><<<ga, 256, 0, stream>>>(h2, w1, f1tb, nullptr, nullptr, hg, nullptr, nullptr, nullptr, 0);
        dim3 gb(768 / 128, 4096 / 64, 2);
        gemm_bt<MODE_OUT, 3072, 1536, 64, 128, 4><<<gb, 256, 0, stream>>>(hg, w2, nullptr, nullptr, g2, nullptr, nullptr, nullptr, out, 0);
    }
    // 8. MLP f-half
    cast2_kernel<<<4608, 256, 0, stream>>>(f1fW, NFC / 4, f2fW, w1);
    {
        dim3 ga(3072 / 128, 4096 / 128, 1);
        gemm_bt<MODE_GELU, 768, 768, 128, 128, 3><<<ga, 256, 0, stream>>>(h2 + (long)4096 * CC, w1, f1fb, nullptr, nullptr, hg, nullptr, nullptr, nullptr, 0);
        dim3 gb(768 / 128, 4096 / 64, 2);
        gemm_bt<MODE_OUT, 3072, 1536, 64, 128, 4><<<gb, 256, 0, stream>>>(hg, w2, nullptr, nullptr, g2, nullptr, nullptr, nullptr, out, 256);
    }
}

// Round 5
// 461.239 us; speedup vs baseline: 1.0213x; 1.0213x over previous
//
#include <hip/hip_runtime.h>
#include <cstdint>

// Problem constants
#define BB 16
#define NN 512
#define CC 768
#define HH 12
#define DD 64
#define HID 3072

typedef __bf16 bf16;
typedef __bf16 bf16x4 __attribute__((ext_vector_type(4)));
typedef __bf16 bf16x8 __attribute__((ext_vector_type(8)));
typedef float f32x4 __attribute__((ext_vector_type(4)));

__device__ __forceinline__ f32x4 mfma16(bf16x8 a, bf16x8 b, f32x4 c) {
    return __builtin_amdgcn_mfma_f32_16x16x32_bf16(a, b, c, 0, 0, 0);
}

__device__ __forceinline__ void g2l16(const bf16* g, bf16* l) {
    __builtin_amdgcn_global_load_lds(
        (const __attribute__((address_space(1))) void*)g,
        (__attribute__((address_space(3))) void*)l, 16, 0, 0);
}

template<int N>
__device__ __forceinline__ void wait_vm() {
    asm volatile("s_waitcnt vmcnt(%0)" :: "n"(N) : "memory");
}

// ---------------- device bodies (reused by fused launches) ----------------
__device__ __forceinline__ void cast_body(
    int i, const float* __restrict__ a, int na4, const float* __restrict__ b, bf16* __restrict__ dst)
{
    const float* s = (i < na4) ? a : b;
    int off = (i < na4) ? i : i - na4;
    f32x4 v = ((const f32x4*)s)[off];
    bf16x4 o;
    #pragma unroll
    for (int e = 0; e < 4; e++) o[e] = (bf16)v[e];
    ((bf16x4*)dst)[i] = o;
}

__device__ __forceinline__ void ln_body(
    int bid, const float* __restrict__ in, bf16* __restrict__ out,
    const float* __restrict__ g, const float* __restrict__ bt)
{
    int w = threadIdx.x >> 6, lane = threadIdx.x & 63;
    long t = bid * 4 + w;
    const float* xr = in + t * CC;
    float vals[12];
    float s = 0.f, sq = 0.f;
    #pragma unroll
    for (int i = 0; i < 3; i++) {
        int off = lane * 4 + i * 256;
        f32x4 v4 = *(const f32x4*)&xr[off];
        #pragma unroll
        for (int e = 0; e < 4; e++) {
            vals[i * 4 + e] = v4[e];
            s += v4[e]; sq += v4[e] * v4[e];
        }
    }
    #pragma unroll
    for (int m = 1; m < 64; m <<= 1) { s += __shfl_xor(s, m); sq += __shfl_xor(sq, m); }
    float mean = s * (1.f / 768.f);
    float var  = sq * (1.f / 768.f) - mean * mean;
    float rstd = rsqrtf(var + 1e-5f);
    bf16* orow = out + t * CC;
    #pragma unroll
    for (int i = 0; i < 3; i++) {
        int off = lane * 4 + i * 256;
        bf16x4 ov;
        #pragma unroll
        for (int e = 0; e < 4; e++)
            ov[e] = (bf16)((vals[i * 4 + e] - mean) * rstd * g[off + e] + bt[off + e]);
        *(bf16x4*)&orow[off] = ov;
    }
}

__device__ __forceinline__ void ln2_body(
    int bid, float* x1, bf16* __restrict__ h2,
    const float* __restrict__ gt, const float* __restrict__ btt,
    const float* __restrict__ gf, const float* __restrict__ btf,
    const float* __restrict__ g2, const float* __restrict__ b2t, const float* __restrict__ b2f)
{
    int w = threadIdx.x >> 6, lane = threadIdx.x & 63;
    long u = bid * 4 + w;      // token 0..8191
    int b = (int)(u >> 9), n = (int)(u & 511);
    bool th = n < 256;
    const float* g  = th ? gt : gf;
    const float* bt = th ? btt : btf;
    const float* b2 = th ? b2t : b2f;
    long h2row = th ? ((long)b * 256 + n) : (4096 + (long)b * 256 + (n - 256));
    float* xr = x1 + u * CC;
    float vals[12];
    float s = 0.f, sq = 0.f;
    #pragma unroll
    for (int i = 0; i < 3; i++) {
        int off = lane * 4 + i * 256;
        f32x4 v4 = *(const f32x4*)&xr[off];
        #pragma unroll
        for (int e = 0; e < 4; e++) {
            vals[i * 4 + e] = v4[e];
            s += v4[e]; sq += v4[e] * v4[e];
        }
    }
    #pragma unroll
    for (int m = 1; m < 64; m <<= 1) { s += __shfl_xor(s, m); sq += __shfl_xor(sq, m); }
    float mean = s * (1.f / 768.f);
    float var  = sq * (1.f / 768.f) - mean * mean;
    float rstd = rsqrtf(var + 1e-5f);
    bf16* orow = h2 + h2row * CC;
    #pragma unroll
    for (int i = 0; i < 3; i++) {
        int off = lane * 4 + i * 256;
        bf16x4 ov;
        f32x4 wv;
        #pragma unroll
        for (int e = 0; e < 4; e++) {
            ov[e] = (bf16)((vals[i * 4 + e] - mean) * rstd * g[off + e] + bt[off + e]);
            wv[e] = vals[i * 4 + e] + g2[off + e] * b2[off + e];
        }
        *(bf16x4*)&orow[off] = ov;
        *(f32x4*)&xr[off] = wv;
    }
}

// ---------------- standalone cast ----------------
__global__ __launch_bounds__(256) void cast2_kernel(
    const float* __restrict__ a, int na4, const float* __restrict__ b, bf16* __restrict__ dst)
{
    cast_body(blockIdx.x * 256 + threadIdx.x, a, na4, b, dst);
}

// ---------------- LN1 fused with Wqkv cast ----------------
__global__ __launch_bounds__(256) void ln1_cast_kernel(
    const float* __restrict__ x, bf16* __restrict__ h,
    const float* __restrict__ g, const float* __restrict__ bt,
    const float* __restrict__ Wqkv, bf16* __restrict__ wqkv)
{
    int bid = blockIdx.x;
    if (bid < 2048) ln_body(bid, x, h, g, bt);
    else            cast_body((bid - 2048) * 256 + threadIdx.x, Wqkv, 442368, nullptr, wqkv);
}

// ---------------- LN2 fused with t-half weight cast ----------------
__global__ __launch_bounds__(256) void ln2_cast_kernel(
    float* x1, bf16* __restrict__ h2,
    const float* __restrict__ gt, const float* __restrict__ btt,
    const float* __restrict__ gf, const float* __restrict__ btf,
    const float* __restrict__ g2, const float* __restrict__ b2t, const float* __restrict__ b2f,
    const float* __restrict__ f1W, const float* __restrict__ f2W, bf16* __restrict__ w1)
{
    int bid = blockIdx.x;
    if (bid < 2048) ln2_body(bid, x1, h2, gt, btt, gf, btf, g2, b2t, b2f);
    else            cast_body((bid - 2048) * 256 + threadIdx.x, f1W, (HID * CC) / 4, f2W, w1);
}

// ---------------- bias precompute, pre-arranged into MFMA C-fragment layout ----------------
// layout: element ((((h*8 + g)*4 + w)*8 + ch)*64 + lane)*16 + (ii*4 + t)
//   == bias[h][row = g*64 + w*16 + (lane>>4)*4 + ii][col = ch*64 + t*16 + (lane&15)]
__global__ __launch_bounds__(256) void bias_kernel(
    const int* __restrict__ rpi, const float* __restrict__ table, bf16* __restrict__ bb)
{
    int flat = blockIdx.x * 256 + threadIdx.x;   // 196608 threads
    int lane = flat & 63;
    int ch   = (flat >> 6) & 7;
    int w    = (flat >> 9) & 3;
    int g    = (flat >> 11) & 7;
    int h    = flat >> 14;
    int row0 = g * 64 + w * 16 + (lane >> 4) * 4;
    int col0 = ch * 64 + (lane & 15);
    bf16x8 v0, v1;
    #pragma unroll
    for (int ii = 0; ii < 4; ii++) {
        #pragma unroll
        for (int t = 0; t < 4; t++) {
            int r = rpi[(row0 + ii) * NN + col0 + t * 16];
            bf16 val = (bf16)table[r * HH + h];
            if (ii < 2) v0[ii * 4 + t] = val;
            else        v1[(ii - 2) * 4 + t] = val;
        }
    }
    bf16* dst = bb + (long)flat * 16;
    *(bf16x8*)dst = v0;
    *(bf16x8*)(dst + 8) = v1;
}

// ------- BMxBN MFMA GEMM, DEPTH-deep LDS ring, counted vmcnt, K-phase stagger -------
// Co-resident blocks (same flat0 mod 256 -> same CU) start at rotated K offsets so their
// barrier/latency phases interleave instead of locking step.
enum { MODE_QKV = 0, MODE_PROJ = 1, MODE_GELU = 2, MODE_OUT = 3 };

template<int MODE, int K, int KCHUNK, int BM, int BN, int DEPTH>
__global__ __launch_bounds__(256, 3) void gemm_bt(
    const bf16* __restrict__ A, const bf16* __restrict__ Btb,
    const float* __restrict__ cbias, const float* residf,
    const float* __restrict__ gamma,
    bf16* __restrict__ outb0, bf16* __restrict__ outb1, bf16* __restrict__ outb2,
    float* outf, int rowbase)
{
    constexpr int AR = BM / 64;    // staging rounds (256 threads x 16B covers 64 rows x 32 cols)
    constexpr int BR = BN / 64;
    constexpr int L  = AR + BR;    // vmem loads per tile per thread
    constexpr int VM = (DEPTH - 1) * L;  // counted vmcnt: tile t landed when <= VM outstanding
    constexpr int NT = KCHUNK / 32;
    constexpr int FM = BM / 32;    // frags per wave (m)
    constexpr int FN = BN / 32;
    __shared__ bf16 lsA[DEPTH][BM * 32];
    __shared__ bf16 lsB[DEPTH][BN * 32];
    int tid = threadIdx.x;
    int lane = tid & 63, w = tid >> 6;
    int wm = w & 1, wn = w >> 1;
    int gx = gridDim.x;
    int nwg = gx * gridDim.y;
    int flat0 = blockIdx.y * gx + blockIdx.x;
    // XCD-aware bijective swizzle (nwg % 8 == 0 for every launch in this file)
    int cpx = nwg >> 3;
    int flat = (flat0 & 7) * cpx + (flat0 >> 3);
    int bx = flat % gx, by = flat / gx;
    // K-phase stagger keyed off ORIGINAL id (co-residency follows dispatch order)
    int ph = ((flat0 >> 8) * 13) % NT;
    long m0 = (long)by * BM;
    long n0 = (long)bx * BN;
    long kb = (long)blockIdx.z * KCHUNK;
    f32x4 acc[FM][FN] = {};
    const bf16* Ab = A + m0 * K + kb;
    const bf16* Bb = Btb + n0 * K + kb;
    int r0 = tid >> 2, kg0 = (tid & 3) * 8;   // 8 bf16 = 16B per lane
    int la = lane & 15, hk = (lane >> 4) * 8;

#define STAGE(DB, KT)                                                                        \
    {                                                                                        \
        long sk_ = (long)(KT) * 32;                                                          \
        _Pragma("unroll")                                                                    \
        for (int rr = 0; rr < AR; rr++)                                                      \
            g2l16(Ab + (long)(r0 + rr * 64) * K + sk_ + kg0, lsA[DB] + (tid + rr * 256) * 8);\
        _Pragma("unroll")                                                                    \
        for (int rr = 0; rr < BR; rr++)                                                      \
            g2l16(Bb + (long)(r0 + rr * 64) * K + sk_ + kg0, lsB[DB] + (tid + rr * 256) * 8);\
    }

    // prologue: stage tiles ph..ph+DEPTH-1 (rotated), no waits
    int kp = ph;
    #pragma unroll
    for (int d = 0; d < DEPTH; d++) {
        STAGE(d, kp)
        kp = (kp + 1 < NT) ? kp + 1 : 0;
    }

    int p = 0, ks = kp;
    for (int t = 0; t < NT; t++) {
        wait_vm<VM>();                          // my share of tile t landed
        __builtin_amdgcn_sched_barrier(0);
        __builtin_amdgcn_s_barrier();           // everyone's share landed
        __builtin_amdgcn_sched_barrier(0);
        bf16x8 af[FM], bfr[FN];
        #pragma unroll
        for (int mi = 0; mi < FM; mi++) af[mi]  = *(bf16x8*)&lsA[p][(wm * (BM / 2) + mi * 16 + la) * 32 + hk];
        #pragma unroll
        for (int ni = 0; ni < FN; ni++) bfr[ni] = *(bf16x8*)&lsB[p][(wn * (BN / 2) + ni * 16 + la) * 32 + hk];
        asm volatile("s_waitcnt lgkmcnt(0)" ::: "memory");
        __builtin_amdgcn_sched_barrier(0);
        __builtin_amdgcn_s_barrier();           // all waves done reading buf p -> safe to re-stage
        __builtin_amdgcn_sched_barrier(0);
        if (t + DEPTH < NT) {
            STAGE(p, ks)
            ks = (ks + 1 < NT) ? ks + 1 : 0;
        }
        __builtin_amdgcn_s_setprio(1);
        #pragma unroll
        for (int mi = 0; mi < FM; mi++)
            #pragma unroll
            for (int ni = 0; ni < FN; ni++)
                acc[mi][ni] = mfma16(af[mi], bfr[ni], acc[mi][ni]);
        __builtin_amdgcn_s_setprio(0);
        p = (p + 1 == DEPTH) ? 0 : p + 1;
    }
#undef STAGE

    int q4 = (lane >> 4) * 4;
    // QKV: the whole block maps into exactly one of q/k/v (768 % BN == 0)
    int sblk = 0, cb0 = 0;
    if constexpr (MODE == MODE_QKV) {
        sblk = (int)(n0 / CC);
        cb0  = (int)n0 - sblk * CC;
    }
    #pragma unroll
    for (int mi = 0; mi < FM; mi++) {
        #pragma unroll
        for (int ni = 0; ni < FN; ni++) {
            long rb = m0 + wm * (BM / 2) + mi * 16 + q4;
            long c  = n0 + wn * (BN / 2) + ni * 16 + la;
            #pragma unroll
            for (int i = 0; i < 4; i++) {
                long r = rb + i;
                float v = acc[mi][ni][i];
                if (MODE == MODE_QKV) {
                    int rem = cb0 + wn * (BN / 2) + ni * 16 + la;
                    int hh = rem >> 6, d = rem & 63;
                    long b = r >> 9, n = r & 511;
                    long dst = (((b * HH + hh) << 9) + n) * 64 + d;
                    if (sblk == 0)      outb0[dst] = (bf16)(v * 0.125f);
                    else if (sblk == 1) outb1[dst] = (bf16)v;
                    else                outb2[dst] = (bf16)v;
                } else if (MODE == MODE_PROJ) {
                    float val = v + cbias[c];
                    long idx = r * CC + c;
                    outf[idx] = residf[idx] + gamma[c] * val;
                } else if (MODE == MODE_GELU) {
                    float val = v + cbias[c];
                    float gl = 0.5f * val * (1.f + erff(val * 0.70710678118f));
                    outb0[r * (long)HID + c] = (bf16)gl;
                } else {  // MODE_OUT: bias pre-added by ln2 writeback; split-K atomic accumulate
                    long grow = (r >> 8) * NN + (r & 255) + rowbase;
                    atomicAdd(outf + grow * CC + c, gamma[c] * v);
                }
            }
        }
    }
}

// ---------------- Flash attention: 128 q-rows per block (two 16-row tiles per wave) ----------------
// grid = b(16) x qt(4) x h(12).  K/V staged once per chunk, reused by both q-sets.
// bias read as 2x16B coalesced loads from pre-arranged fragment layout.
// row-sum l accumulated via mfma(P, ones) (rides the MFMA pipe; no sum-shuffles).
__global__ __launch_bounds__(256, 3) void attn_kernel(
    const bf16* __restrict__ q, const bf16* __restrict__ k, const bf16* __restrict__ v,
    const bf16* __restrict__ bb, bf16* __restrict__ o)
{
    __shared__ bf16 lsK[64 * 72];
    __shared__ bf16 lsVT[64 * 68];
    __shared__ bf16 lsP[4][2][16 * 76];
    int tid = threadIdx.x, lane = tid & 63, w = tid >> 6;
    int b  = blockIdx.x & 15;
    int qt = (blockIdx.x >> 4) & 3;
    int h  = blockIdx.x >> 6;
    long base = (long)(b * HH + h) * NN * DD;
    int la = lane & 15, hi = lane >> 4;
    int qr0 = qt * 128 + w * 16;           // set A rows; set B = +64
    // bias base for (h, granule=qt*2, w); granule stride = 4*8*1024 = 32768
    const bf16* bb0 = bb + ((long)((h * 8 + qt * 2) * 4 + w) * 8) * 1024 + lane * 16;

    bf16x8 qA0 = *(const bf16x8*)&q[base + (long)(qr0 + la) * 64 + hi * 8];
    bf16x8 qA1 = *(const bf16x8*)&q[base + (long)(qr0 + la) * 64 + 32 + hi * 8];
    bf16x8 qB0 = *(const bf16x8*)&q[base + (long)(qr0 + 64 + la) * 64 + hi * 8];
    bf16x8 qB1 = *(const bf16x8*)&q[base + (long)(qr0 + 64 + la) * 64 + 32 + hi * 8];
    f32x4 ofA[4] = {}, ofB[4] = {};
    f32x4 lfA = {}, lfB = {};
    float mA[4], mB[4];
    #pragma unroll
    for (int i = 0; i < 4; i++) { mA[i] = -1e30f; mB[i] = -1e30f; }
    bf16x8 ones;
    #pragma unroll
    for (int e = 0; e < 8; e++) ones[e] = (bf16)1.0f;

    int jr = tid >> 2, dg16 = (tid & 3) * 16;
    for (int ch = 0; ch < 8; ch++) {
        int j0 = ch * 64;
        const bf16* krow = &k[base + (long)(j0 + jr) * 64 + dg16];
        *(bf16x8*)&lsK[jr * 72 + dg16]     = *(const bf16x8*)krow;
        *(bf16x8*)&lsK[jr * 72 + dg16 + 8] = *(const bf16x8*)(krow + 8);
        const bf16* vrow = &v[base + (long)(j0 + jr) * 64 + dg16];
        bf16x8 v0 = *(const bf16x8*)vrow;
        bf16x8 v1 = *(const bf16x8*)(vrow + 8);
        #pragma unroll
        for (int e = 0; e < 8; e++) {
            lsVT[(dg16 + e) * 68 + jr]     = v0[e];
            lsVT[(dg16 + 8 + e) * 68 + jr] = v1[e];
        }
        __syncthreads();

        // QK^T, K-frags shared by both q-sets
        f32x4 sA[4] = {}, sB[4] = {};
        #pragma unroll
        for (int t = 0; t < 4; t++) {
            bf16x8 kf0 = *(bf16x8*)&lsK[(t * 16 + la) * 72 + hi * 8];
            bf16x8 kf1 = *(bf16x8*)&lsK[(t * 16 + la) * 72 + 32 + hi * 8];
            sA[t] = mfma16(qA0, kf0, sA[t]);
            sA[t] = mfma16(qA1, kf1, sA[t]);
            sB[t] = mfma16(qB0, kf0, sB[t]);
            sB[t] = mfma16(qB1, kf1, sB[t]);
        }
        // bias: 2x16B coalesced loads per set
        {
            const bf16* bpA = bb0 + ch * 1024;
            const bf16* bpB = bpA + 32768;
            bf16x8 a0 = *(const bf16x8*)bpA, a1 = *(const bf16x8*)(bpA + 8);
            bf16x8 c0 = *(const bf16x8*)bpB, c1 = *(const bf16x8*)(bpB + 8);
            #pragma unroll
            for (int t = 0; t < 4; t++) {
                sA[t][0] += (float)a0[t];     sA[t][1] += (float)a0[4 + t];
                sA[t][2] += (float)a1[t];     sA[t][3] += (float)a1[4 + t];
                sB[t][0] += (float)c0[t];     sB[t][1] += (float)c0[4 + t];
                sB[t][2] += (float)c1[t];     sB[t][3] += (float)c1[4 + t];
            }
        }
        // online softmax (max-reduce via shuffles; sum deferred to mfma(P, ones))
        #define SM_SET(S, M, OF, LF, PSET)                                               \
        {                                                                                \
            float alpha[4];                                                              \
            _Pragma("unroll")                                                            \
            for (int i = 0; i < 4; i++) {                                                \
                float mx = fmaxf(fmaxf(S[0][i], S[1][i]), fmaxf(S[2][i], S[3][i]));      \
                _Pragma("unroll")                                                        \
                for (int msk = 1; msk < 16; msk <<= 1) mx = fmaxf(mx, __shfl_xor(mx, msk)); \
                float mn = fmaxf(M[i], mx);                                              \
                alpha[i] = __expf(M[i] - mn);                                            \
                M[i] = mn;                                                               \
                _Pragma("unroll")                                                        \
                for (int t = 0; t < 4; t++) S[t][i] = __expf(S[t][i] - mn);              \
            }                                                                            \
            _Pragma("unroll")                                                            \
            for (int t = 0; t < 4; t++) {                                                \
                _Pragma("unroll")                                                        \
                for (int i = 0; i < 4; i++) OF[t][i] *= alpha[i];                        \
            }                                                                            \
            _Pragma("unroll")                                                            \
            for (int i = 0; i < 4; i++) LF[i] *= alpha[i];                               \
            _Pragma("unroll")                                                            \
            for (int i = 0; i < 4; i++) {                                                \
                _Pragma("unroll")                                                        \
                for (int t = 0; t < 4; t++)                                              \
                    lsP[w][PSET][(hi * 4 + i) * 76 + t * 16 + la] = (bf16)S[t][i];       \
            }                                                                            \
        }
        SM_SET(sA, mA, ofA, lfA, 0)
        SM_SET(sB, mB, ofB, lfB, 1)
        #undef SM_SET

        bf16x8 pA0 = *(bf16x8*)&lsP[w][0][la * 76 + hi * 8];
        bf16x8 pA1 = *(bf16x8*)&lsP[w][0][la * 76 + 32 + hi * 8];
        bf16x8 pB0 = *(bf16x8*)&lsP[w][1][la * 76 + hi * 8];
        bf16x8 pB1 = *(bf16x8*)&lsP[w][1][la * 76 + 32 + hi * 8];
        #pragma unroll
        for (int t = 0; t < 4; t++) {
            bf16x8 vf0 = *(bf16x8*)&lsVT[(t * 16 + la) * 68 + hi * 8];
            bf16x8 vf1 = *(bf16x8*)&lsVT[(t * 16 + la) * 68 + 32 + hi * 8];
            ofA[t] = mfma16(pA0, vf0, ofA[t]);
            ofA[t] = mfma16(pA1, vf1, ofA[t]);
            ofB[t] = mfma16(pB0, vf0, ofB[t]);
            ofB[t] = mfma16(pB1, vf1, ofB[t]);
        }
        lfA = mfma16(pA0, ones, lfA);
        lfA = mfma16(pA1, ones, lfA);
        lfB = mfma16(pB0, ones, lfB);
        lfB = mfma16(pB1, ones, lfB);
        __syncthreads();
    }
    float invA[4], invB[4];
    #pragma unroll
    for (int i = 0; i < 4; i++) { invA[i] = 1.f / lfA[i]; invB[i] = 1.f / lfB[i]; }
    #pragma unroll
    for (int t = 0; t < 4; t++) {
        #pragma unroll
        for (int i = 0; i < 4; i++) {
            long rowA = (long)b * NN + qr0 + hi * 4 + i;
            o[rowA * CC + h * 64 + t * 16 + la]        = (bf16)(ofA[t][i] * invA[i]);
            o[(rowA + 64) * CC + h * 64 + t * 16 + la] = (bf16)(ofB[t][i] * invB[i]);
        }
    }
}

extern "C" void kernel_launch(void* const* d_in, const int* in_sizes, int n_in,
                              void* d_out, int out_size, void* d_ws, size_t ws_size,
                              hipStream_t stream)
{
    const float* x     = (const float*)d_in[0];
    const int*   rpi   = (const int*)d_in[2];
    const float* Wqkv  = (const float*)d_in[3];
    const float* Wproj = (const float*)d_in[4];
    const float* bproj = (const float*)d_in[5];
    const float* rtab  = (const float*)d_in[6];
    const float* ln1g  = (const float*)d_in[7];
    const float* ln1b  = (const float*)d_in[8];
    const float* g1    = (const float*)d_in[9];
    const float* g2    = (const float*)d_in[10];
    const float* ln2tg = (const float*)d_in[11];
    const float* ln2tb = (const float*)d_in[12];
    const float* f1tW  = (const float*)d_in[13];
    const float* f1tb  = (const float*)d_in[14];
    const float* f2tW  = (const float*)d_in[15];
    const float* f2tb  = (const float*)d_in[16];
    const float* ln2fg = (const float*)d_in[17];
    const float* ln2fb = (const float*)d_in[18];
    const float* f1fW  = (const float*)d_in[19];
    const float* f1fb  = (const float*)d_in[20];
    const float* f2fW  = (const float*)d_in[21];
    const float* f2fb  = (const float*)d_in[22];
    float* out = (float*)d_out;

    // ws: 4 regions x 12.58MB bf16 = 50.33MB.
    //  rA: q  -> Wproj(bf16) -> h2        rB: k -> hg lo     rC: v -> hg hi
    //  rD: Wqkv(bf16) -> o -> MLP weight pairs (w1,w2 bf16)
    // d_out: h (bf16 LN1) -> bias table (bf16) -> x1 (fp32 residual/result)
    char* ws = (char*)d_ws;
    const long TOKC = (long)BB * NN * CC;        // 6291456
    const int  NFC  = HID * CC;                  // 2359296
    bf16* rA = (bf16*)ws;
    bf16* rB = rA + TOKC;
    bf16* rC = rB + TOKC;
    bf16* rD = rC + TOKC;

    bf16 *qb = rA, *kb = rB, *vb = rC, *o = rD;
    bf16  *h    = (bf16*)d_out;
    bf16  *bbt  = (bf16*)d_out;
    float *x1   = out;
    bf16  *wqkv = rD;     // before o
    bf16  *wpro = rA;     // after q dies
    bf16  *h2   = rA;     // after Wproj dies
    bf16  *hg   = rB;     // spans rB+rC
    bf16  *w1   = rD;     // after o dies
    bf16  *w2   = rD + NFC;

    // 1. LN1 (fp32 x -> bf16 h) fused with Wqkv cast (rD; o not yet written)
    ln1_cast_kernel<<<2048 + 1728, 256, 0, stream>>>(x, h, ln1g, ln1b, Wqkv, wqkv);
    // 2. QKV projection
    {
        dim3 g(2304 / 128, 8192 / 128, 1);
        gemm_bt<MODE_QKV, 768, 768, 128, 128, 3><<<g, 256, 0, stream>>>(h, wqkv, nullptr, nullptr, nullptr, qb, kb, vb, nullptr, 0);
    }
    // 3. bias table in fragment layout (h dead)
    bias_kernel<<<768, 256, 0, stream>>>(rpi, rtab, bbt);
    // 4. attention (reads rA,rB,rC,bbt; writes o=rD; wqkv dead)
    attn_kernel<<<BB * 4 * HH, 256, 0, stream>>>(qb, kb, vb, bbt, o);
    // 5a. cast Wproj -> bf16 (rA; q dead)
    cast2_kernel<<<576, 256, 0, stream>>>(Wproj, 147456, nullptr, wpro);
    // 5b. proj + residual -> x1 (overwrites d_out; bbt dead); 64x128 tile -> 768 blocks (3/CU)
    {
        dim3 g(768 / 128, 8192 / 64, 1);
        gemm_bt<MODE_PROJ, 768, 768, 64, 128, 4><<<g, 256, 0, stream>>>(o, wpro, bproj, x, g1, nullptr, nullptr, nullptr, x1, 0);
    }
    // 6. LN2 both halves -> h2 (rA; Wproj dead), x1 += g2*fc2_bias; fused t-weight cast (rD; o dead)
    ln2_cast_kernel<<<2048 + 4608, 256, 0, stream>>>(x1, h2, ln2tg, ln2tb, ln2fg, ln2fb, g2, f2tb, f2fb,
                                                     f1tW, f2tW, w1);
    // 7. MLP t-half: GELU, OUT split-K=2 with 64x128 tile (3/CU)
    {
        dim3 ga(3072 / 128, 4096 / 128, 1);
        gemm_bt<MODE_GELU, 768, 768, 128, 128, 3><<<ga, 256, 0, stream>>>(h2, w1, f1tb, nullptr, nullptr, hg, nullptr, nullptr, nullptr, 0);
        dim3 gb(768 / 128, 4096 / 64, 2);
        gemm_bt<MODE_OUT, 3072, 1536, 64, 128, 4><<<gb, 256, 0, stream>>>(hg, w2, nullptr, nullptr, g2, nullptr, nullptr, nullptr, out, 0);
    }
    // 8. MLP f-half
    cast2_kernel<<<4608, 256, 0, stream>>>(f1fW, NFC / 4, f2fW, w1);
    {
        dim3 ga(3072 / 128, 4096 / 128, 1);
        gemm_bt<MODE_GELU, 768, 768, 128, 128, 3><<<ga, 256, 0, stream>>>(h2 + (long)4096 * CC, w1, f1fb, nullptr, nullptr, hg, nullptr, nullptr, nullptr, 0);
        dim3 gb(768 / 128, 4096 / 64, 2);
        gemm_bt<MODE_OUT, 3072, 1536, 64, 128, 4><<<gb, 256, 0, stream>>>(hg, w2, nullptr, nullptr, g2, nullptr, nullptr, nullptr, out, 256);
    }
}

// Round 6
// 449.201 us; speedup vs baseline: 1.0486x; 1.0268x over previous
//
#include <hip/hip_runtime.h>
#include <cstdint>

// Problem constants
#define BB 16
#define NN 512
#define CC 768
#define HH 12
#define DD 64
#define HID 3072

typedef __bf16 bf16;
typedef __bf16 bf16x4 __attribute__((ext_vector_type(4)));
typedef __bf16 bf16x8 __attribute__((ext_vector_type(8)));
typedef float f32x4 __attribute__((ext_vector_type(4)));

__device__ __forceinline__ f32x4 mfma16(bf16x8 a, bf16x8 b, f32x4 c) {
    return __builtin_amdgcn_mfma_f32_16x16x32_bf16(a, b, c, 0, 0, 0);
}

__device__ __forceinline__ void g2l16(const bf16* g, bf16* l) {
    __builtin_amdgcn_global_load_lds(
        (const __attribute__((address_space(1))) void*)g,
        (__attribute__((address_space(3))) void*)l, 16, 0, 0);
}

template<int N>
__device__ __forceinline__ void wait_vm() {
    asm volatile("s_waitcnt vmcnt(%0)" :: "n"(N) : "memory");
}

// ---------------- device bodies (reused by fused launches) ----------------
__device__ __forceinline__ void cast_body(
    int i, const float* __restrict__ a, int na4, const float* __restrict__ b, bf16* __restrict__ dst)
{
    const float* s = (i < na4) ? a : b;
    int off = (i < na4) ? i : i - na4;
    f32x4 v = ((const f32x4*)s)[off];
    bf16x4 o;
    #pragma unroll
    for (int e = 0; e < 4; e++) o[e] = (bf16)v[e];
    ((bf16x4*)dst)[i] = o;
}

__device__ __forceinline__ void ln_body(
    int bid, const float* __restrict__ in, bf16* __restrict__ out,
    const float* __restrict__ g, const float* __restrict__ bt)
{
    int w = threadIdx.x >> 6, lane = threadIdx.x & 63;
    long t = bid * 4 + w;
    const float* xr = in + t * CC;
    float vals[12];
    float s = 0.f, sq = 0.f;
    #pragma unroll
    for (int i = 0; i < 3; i++) {
        int off = lane * 4 + i * 256;
        f32x4 v4 = *(const f32x4*)&xr[off];
        #pragma unroll
        for (int e = 0; e < 4; e++) {
            vals[i * 4 + e] = v4[e];
            s += v4[e]; sq += v4[e] * v4[e];
        }
    }
    #pragma unroll
    for (int m = 1; m < 64; m <<= 1) { s += __shfl_xor(s, m); sq += __shfl_xor(sq, m); }
    float mean = s * (1.f / 768.f);
    float var  = sq * (1.f / 768.f) - mean * mean;
    float rstd = rsqrtf(var + 1e-5f);
    bf16* orow = out + t * CC;
    #pragma unroll
    for (int i = 0; i < 3; i++) {
        int off = lane * 4 + i * 256;
        bf16x4 ov;
        #pragma unroll
        for (int e = 0; e < 4; e++)
            ov[e] = (bf16)((vals[i * 4 + e] - mean) * rstd * g[off + e] + bt[off + e]);
        *(bf16x4*)&orow[off] = ov;
    }
}

__device__ __forceinline__ void ln2_body(
    int bid, float* x1, bf16* __restrict__ h2,
    const float* __restrict__ gt, const float* __restrict__ btt,
    const float* __restrict__ gf, const float* __restrict__ btf,
    const float* __restrict__ g2, const float* __restrict__ b2t, const float* __restrict__ b2f)
{
    int w = threadIdx.x >> 6, lane = threadIdx.x & 63;
    long u = bid * 4 + w;      // token 0..8191
    int b = (int)(u >> 9), n = (int)(u & 511);
    bool th = n < 256;
    const float* g  = th ? gt : gf;
    const float* bt = th ? btt : btf;
    const float* b2 = th ? b2t : b2f;
    long h2row = th ? ((long)b * 256 + n) : (4096 + (long)b * 256 + (n - 256));
    float* xr = x1 + u * CC;
    float vals[12];
    float s = 0.f, sq = 0.f;
    #pragma unroll
    for (int i = 0; i < 3; i++) {
        int off = lane * 4 + i * 256;
        f32x4 v4 = *(const f32x4*)&xr[off];
        #pragma unroll
        for (int e = 0; e < 4; e++) {
            vals[i * 4 + e] = v4[e];
            s += v4[e]; sq += v4[e] * v4[e];
        }
    }
    #pragma unroll
    for (int m = 1; m < 64; m <<= 1) { s += __shfl_xor(s, m); sq += __shfl_xor(sq, m); }
    float mean = s * (1.f / 768.f);
    float var  = sq * (1.f / 768.f) - mean * mean;
    float rstd = rsqrtf(var + 1e-5f);
    bf16* orow = h2 + h2row * CC;
    #pragma unroll
    for (int i = 0; i < 3; i++) {
        int off = lane * 4 + i * 256;
        bf16x4 ov;
        f32x4 wv;
        #pragma unroll
        for (int e = 0; e < 4; e++) {
            ov[e] = (bf16)((vals[i * 4 + e] - mean) * rstd * g[off + e] + bt[off + e]);
            wv[e] = vals[i * 4 + e] + g2[off + e] * b2[off + e];
        }
        *(bf16x4*)&orow[off] = ov;
        *(f32x4*)&xr[off] = wv;
    }
}

// ---------------- standalone cast ----------------
__global__ __launch_bounds__(256) void cast2_kernel(
    const float* __restrict__ a, int na4, const float* __restrict__ b, bf16* __restrict__ dst)
{
    cast_body(blockIdx.x * 256 + threadIdx.x, a, na4, b, dst);
}

// ---------------- LN1 fused with Wqkv cast ----------------
__global__ __launch_bounds__(256) void ln1_cast_kernel(
    const float* __restrict__ x, bf16* __restrict__ h,
    const float* __restrict__ g, const float* __restrict__ bt,
    const float* __restrict__ Wqkv, bf16* __restrict__ wqkv)
{
    int bid = blockIdx.x;
    if (bid < 2048) ln_body(bid, x, h, g, bt);
    else            cast_body((bid - 2048) * 256 + threadIdx.x, Wqkv, 442368, nullptr, wqkv);
}

// ---------------- LN2 fused with t-half weight cast ----------------
__global__ __launch_bounds__(256) void ln2_cast_kernel(
    float* x1, bf16* __restrict__ h2,
    const float* __restrict__ gt, const float* __restrict__ btt,
    const float* __restrict__ gf, const float* __restrict__ btf,
    const float* __restrict__ g2, const float* __restrict__ b2t, const float* __restrict__ b2f,
    const float* __restrict__ f1W, const float* __restrict__ f2W, bf16* __restrict__ w1)
{
    int bid = blockIdx.x;
    if (bid < 2048) ln2_body(bid, x1, h2, gt, btt, gf, btf, g2, b2t, b2f);
    else            cast_body((bid - 2048) * 256 + threadIdx.x, f1W, (HID * CC) / 4, f2W, w1);
}

// ---------------- bias precompute, pre-arranged into MFMA C-fragment layout ----------------
// layout: element ((((h*8 + g)*4 + w)*8 + ch)*64 + lane)*16 + (ii*4 + t)
//   == bias[h][row = g*64 + w*16 + (lane>>4)*4 + ii][col = ch*64 + t*16 + (lane&15)]
__global__ __launch_bounds__(256) void bias_kernel(
    const int* __restrict__ rpi, const float* __restrict__ table, bf16* __restrict__ bb)
{
    int flat = blockIdx.x * 256 + threadIdx.x;   // 196608 threads
    int lane = flat & 63;
    int ch   = (flat >> 6) & 7;
    int w    = (flat >> 9) & 3;
    int g    = (flat >> 11) & 7;
    int h    = flat >> 14;
    int row0 = g * 64 + w * 16 + (lane >> 4) * 4;
    int col0 = ch * 64 + (lane & 15);
    bf16x8 v0, v1;
    #pragma unroll
    for (int ii = 0; ii < 4; ii++) {
        #pragma unroll
        for (int t = 0; t < 4; t++) {
            int r = rpi[(row0 + ii) * NN + col0 + t * 16];
            bf16 val = (bf16)table[r * HH + h];
            if (ii < 2) v0[ii * 4 + t] = val;
            else        v1[(ii - 2) * 4 + t] = val;
        }
    }
    bf16* dst = bb + (long)flat * 16;
    *(bf16x8*)dst = v0;
    *(bf16x8*)(dst + 8) = v1;
}

// ------- BMxBN MFMA GEMM, single-barrier DEPTH-ring, counted vmcnt: C = A @ Bt^T -------
// Per iteration exactly ONE s_barrier: vmcnt(VM) -> barrier -> ds_read frags[t] ->
// stage tile t+DEPTH-1 into the buffer freed at t-1 (WAR ordered by prev iter's
// lgkmcnt(0), which precedes this barrier) -> lgkmcnt(0) -> MFMA. Loads are never
// drained in the loop; last iteration peeled with vmcnt(0).
enum { MODE_QKV = 0, MODE_PROJ = 1, MODE_GELU = 2, MODE_OUT = 3 };

template<int MODE, int K, int KCHUNK, int BM, int BN, int DEPTH>
__global__ __launch_bounds__(256, 3) void gemm_bt(
    const bf16* __restrict__ A, const bf16* __restrict__ Btb,
    const float* __restrict__ cbias, const float* residf,
    const float* __restrict__ gamma,
    bf16* __restrict__ outb0, bf16* __restrict__ outb1, bf16* __restrict__ outb2,
    float* outf, int rowbase)
{
    constexpr int AR = BM / 64;    // staging rounds (256 threads x 16B covers 64 rows x 32 cols)
    constexpr int BR = BN / 64;
    constexpr int L  = AR + BR;    // vmem loads per tile per thread
    constexpr int VM = (DEPTH - 2) * L;  // counted: tile t landed, DEPTH-2 newer tiles in flight
    constexpr int NT = KCHUNK / 32;
    static_assert(NT > DEPTH, "");
    constexpr int FM = BM / 32;    // frags per wave (m)
    constexpr int FN = BN / 32;
    __shared__ bf16 lsA[DEPTH][BM * 32];
    __shared__ bf16 lsB[DEPTH][BN * 32];
    int tid = threadIdx.x;
    int lane = tid & 63, w = tid >> 6;
    int wm = w & 1, wn = w >> 1;
    int gx = gridDim.x;
    int nwg = gx * gridDim.y;
    int flat = blockIdx.y * gx + blockIdx.x;
    // XCD-aware bijective swizzle (nwg % 8 == 0 for every launch in this file)
    int cpx = nwg >> 3;
    flat = (flat & 7) * cpx + (flat >> 3);
    int bx = flat % gx, by = flat / gx;
    long m0 = (long)by * BM;
    long n0 = (long)bx * BN;
    long kb = (long)blockIdx.z * KCHUNK;
    f32x4 acc[FM][FN] = {};
    const bf16* Ab = A + m0 * K + kb;
    const bf16* Bb = Btb + n0 * K + kb;
    int r0 = tid >> 2, kg0 = (tid & 3) * 8;   // 8 bf16 = 16B per lane
    int la = lane & 15, hk = (lane >> 4) * 8;

#define STAGE(DB, KT)                                                                        \
    {                                                                                        \
        long sk_ = (long)(KT) * 32;                                                          \
        _Pragma("unroll")                                                                    \
        for (int rr = 0; rr < AR; rr++)                                                      \
            g2l16(Ab + (long)(r0 + rr * 64) * K + sk_ + kg0, lsA[DB] + (tid + rr * 256) * 8);\
        _Pragma("unroll")                                                                    \
        for (int rr = 0; rr < BR; rr++)                                                      \
            g2l16(Bb + (long)(r0 + rr * 64) * K + sk_ + kg0, lsB[DB] + (tid + rr * 256) * 8);\
    }

    // prologue: stage tiles 0..DEPTH-2 (one ring slot stays free), no waits
    #pragma unroll
    for (int d = 0; d < DEPTH - 1; d++) STAGE(d, d)

    int p = 0;
    for (int t = 0; t < NT - 1; t++) {
        wait_vm<VM>();                          // my share of tile t landed
        __builtin_amdgcn_sched_barrier(0);
        __builtin_amdgcn_s_barrier();           // everyone's share landed; t-1 reads retired
        __builtin_amdgcn_sched_barrier(0);
        bf16x8 af[FM], bfr[FN];
        #pragma unroll
        for (int mi = 0; mi < FM; mi++) af[mi]  = *(bf16x8*)&lsA[p][(wm * (BM / 2) + mi * 16 + la) * 32 + hk];
        #pragma unroll
        for (int ni = 0; ni < FN; ni++) bfr[ni] = *(bf16x8*)&lsB[p][(wn * (BN / 2) + ni * 16 + la) * 32 + hk];
        if (t + DEPTH - 1 < NT) {
            int pd = p + DEPTH - 1; if (pd >= DEPTH) pd -= DEPTH;   // buffer freed at t-1
            STAGE(pd, t + DEPTH - 1)
        }
        asm volatile("s_waitcnt lgkmcnt(0)" ::: "memory");
        __builtin_amdgcn_sched_barrier(0);
        __builtin_amdgcn_s_setprio(1);
        #pragma unroll
        for (int mi = 0; mi < FM; mi++)
            #pragma unroll
            for (int ni = 0; ni < FN; ni++)
                acc[mi][ni] = mfma16(af[mi], bfr[ni], acc[mi][ni]);
        __builtin_amdgcn_s_setprio(0);
        p = (p + 1 == DEPTH) ? 0 : p + 1;
    }
    // last iteration: nothing left in flight to count -> full drain
    {
        wait_vm<0>();
        __builtin_amdgcn_sched_barrier(0);
        __builtin_amdgcn_s_barrier();
        __builtin_amdgcn_sched_barrier(0);
        bf16x8 af[FM], bfr[FN];
        #pragma unroll
        for (int mi = 0; mi < FM; mi++) af[mi]  = *(bf16x8*)&lsA[p][(wm * (BM / 2) + mi * 16 + la) * 32 + hk];
        #pragma unroll
        for (int ni = 0; ni < FN; ni++) bfr[ni] = *(bf16x8*)&lsB[p][(wn * (BN / 2) + ni * 16 + la) * 32 + hk];
        asm volatile("s_waitcnt lgkmcnt(0)" ::: "memory");
        __builtin_amdgcn_sched_barrier(0);
        __builtin_amdgcn_s_setprio(1);
        #pragma unroll
        for (int mi = 0; mi < FM; mi++)
            #pragma unroll
            for (int ni = 0; ni < FN; ni++)
                acc[mi][ni] = mfma16(af[mi], bfr[ni], acc[mi][ni]);
        __builtin_amdgcn_s_setprio(0);
    }
#undef STAGE

    int q4 = (lane >> 4) * 4;
    // QKV: the whole block maps into exactly one of q/k/v (768 % BN == 0)
    int sblk = 0, cb0 = 0;
    if constexpr (MODE == MODE_QKV) {
        sblk = (int)(n0 / CC);
        cb0  = (int)n0 - sblk * CC;
    }
    #pragma unroll
    for (int mi = 0; mi < FM; mi++) {
        #pragma unroll
        for (int ni = 0; ni < FN; ni++) {
            long rb = m0 + wm * (BM / 2) + mi * 16 + q4;
            long c  = n0 + wn * (BN / 2) + ni * 16 + la;
            #pragma unroll
            for (int i = 0; i < 4; i++) {
                long r = rb + i;
                float v = acc[mi][ni][i];
                if (MODE == MODE_QKV) {
                    int rem = cb0 + wn * (BN / 2) + ni * 16 + la;
                    int hh = rem >> 6, d = rem & 63;
                    long b = r >> 9, n = r & 511;
                    long dst = (((b * HH + hh) << 9) + n) * 64 + d;
                    if (sblk == 0)      outb0[dst] = (bf16)(v * 0.125f);
                    else if (sblk == 1) outb1[dst] = (bf16)v;
                    else                outb2[dst] = (bf16)v;
                } else if (MODE == MODE_PROJ) {
                    float val = v + cbias[c];
                    long idx = r * CC + c;
                    outf[idx] = residf[idx] + gamma[c] * val;
                } else if (MODE == MODE_GELU) {
                    float val = v + cbias[c];
                    float gl = 0.5f * val * (1.f + erff(val * 0.70710678118f));
                    outb0[r * (long)HID + c] = (bf16)gl;
                } else {  // MODE_OUT: bias pre-added by ln2 writeback; split-K atomic accumulate
                    long grow = (r >> 8) * NN + (r & 255) + rowbase;
                    atomicAdd(outf + grow * CC + c, gamma[c] * v);
                }
            }
        }
    }
}

// ---------------- Flash attention: 128 q-rows per block (two 16-row tiles per wave) ----------------
// grid = b(16) x qt(4) x h(12).  K/V staged once per chunk, reused by both q-sets.
// bias read as 2x16B coalesced loads from pre-arranged fragment layout.
// row-sum l accumulated via mfma(P, ones) (rides the MFMA pipe; no sum-shuffles).
__global__ __launch_bounds__(256, 3) void attn_kernel(
    const bf16* __restrict__ q, const bf16* __restrict__ k, const bf16* __restrict__ v,
    const bf16* __restrict__ bb, bf16* __restrict__ o)
{
    __shared__ bf16 lsK[64 * 72];
    __shared__ bf16 lsVT[64 * 68];
    __shared__ bf16 lsP[4][2][16 * 76];
    int tid = threadIdx.x, lane = tid & 63, w = tid >> 6;
    int b  = blockIdx.x & 15;
    int qt = (blockIdx.x >> 4) & 3;
    int h  = blockIdx.x >> 6;
    long base = (long)(b * HH + h) * NN * DD;
    int la = lane & 15, hi = lane >> 4;
    int qr0 = qt * 128 + w * 16;           // set A rows; set B = +64
    // bias base for (h, granule=qt*2, w); granule stride = 4*8*1024 = 32768
    const bf16* bb0 = bb + ((long)((h * 8 + qt * 2) * 4 + w) * 8) * 1024 + lane * 16;

    bf16x8 qA0 = *(const bf16x8*)&q[base + (long)(qr0 + la) * 64 + hi * 8];
    bf16x8 qA1 = *(const bf16x8*)&q[base + (long)(qr0 + la) * 64 + 32 + hi * 8];
    bf16x8 qB0 = *(const bf16x8*)&q[base + (long)(qr0 + 64 + la) * 64 + hi * 8];
    bf16x8 qB1 = *(const bf16x8*)&q[base + (long)(qr0 + 64 + la) * 64 + 32 + hi * 8];
    f32x4 ofA[4] = {}, ofB[4] = {};
    f32x4 lfA = {}, lfB = {};
    float mA[4], mB[4];
    #pragma unroll
    for (int i = 0; i < 4; i++) { mA[i] = -1e30f; mB[i] = -1e30f; }
    bf16x8 ones;
    #pragma unroll
    for (int e = 0; e < 8; e++) ones[e] = (bf16)1.0f;

    int jr = tid >> 2, dg16 = (tid & 3) * 16;
    for (int ch = 0; ch < 8; ch++) {
        int j0 = ch * 64;
        const bf16* krow = &k[base + (long)(j0 + jr) * 64 + dg16];
        *(bf16x8*)&lsK[jr * 72 + dg16]     = *(const bf16x8*)krow;
        *(bf16x8*)&lsK[jr * 72 + dg16 + 8] = *(const bf16x8*)(krow + 8);
        const bf16* vrow = &v[base + (long)(j0 + jr) * 64 + dg16];
        bf16x8 v0 = *(const bf16x8*)vrow;
        bf16x8 v1 = *(const bf16x8*)(vrow + 8);
        #pragma unroll
        for (int e = 0; e < 8; e++) {
            lsVT[(dg16 + e) * 68 + jr]     = v0[e];
            lsVT[(dg16 + 8 + e) * 68 + jr] = v1[e];
        }
        __syncthreads();

        // QK^T, K-frags shared by both q-sets
        f32x4 sA[4] = {}, sB[4] = {};
        #pragma unroll
        for (int t = 0; t < 4; t++) {
            bf16x8 kf0 = *(bf16x8*)&lsK[(t * 16 + la) * 72 + hi * 8];
            bf16x8 kf1 = *(bf16x8*)&lsK[(t * 16 + la) * 72 + 32 + hi * 8];
            sA[t] = mfma16(qA0, kf0, sA[t]);
            sA[t] = mfma16(qA1, kf1, sA[t]);
            sB[t] = mfma16(qB0, kf0, sB[t]);
            sB[t] = mfma16(qB1, kf1, sB[t]);
        }
        // bias: 2x16B coalesced loads per set
        {
            const bf16* bpA = bb0 + ch * 1024;
            const bf16* bpB = bpA + 32768;
            bf16x8 a0 = *(const bf16x8*)bpA, a1 = *(const bf16x8*)(bpA + 8);
            bf16x8 c0 = *(const bf16x8*)bpB, c1 = *(const bf16x8*)(bpB + 8);
            #pragma unroll
            for (int t = 0; t < 4; t++) {
                sA[t][0] += (float)a0[t];     sA[t][1] += (float)a0[4 + t];
                sA[t][2] += (float)a1[t];     sA[t][3] += (float)a1[4 + t];
                sB[t][0] += (float)c0[t];     sB[t][1] += (float)c0[4 + t];
                sB[t][2] += (float)c1[t];     sB[t][3] += (float)c1[4 + t];
            }
        }
        // online softmax (max-reduce via shuffles; sum deferred to mfma(P, ones))
        #define SM_SET(S, M, OF, LF, PSET)                                               \
        {                                                                                \
            float alpha[4];                                                              \
            _Pragma("unroll")                                                            \
            for (int i = 0; i < 4; i++) {                                                \
                float mx = fmaxf(fmaxf(S[0][i], S[1][i]), fmaxf(S[2][i], S[3][i]));      \
                _Pragma("unroll")                                                        \
                for (int msk = 1; msk < 16; msk <<= 1) mx = fmaxf(mx, __shfl_xor(mx, msk)); \
                float mn = fmaxf(M[i], mx);                                              \
                alpha[i] = __expf(M[i] - mn);                                            \
                M[i] = mn;                                                               \
                _Pragma("unroll")                                                        \
                for (int t = 0; t < 4; t++) S[t][i] = __expf(S[t][i] - mn);              \
            }                                                                            \
            _Pragma("unroll")                                                            \
            for (int t = 0; t < 4; t++) {                                                \
                _Pragma("unroll")                                                        \
                for (int i = 0; i < 4; i++) OF[t][i] *= alpha[i];                        \
            }                                                                            \
            _Pragma("unroll")                                                            \
            for (int i = 0; i < 4; i++) LF[i] *= alpha[i];                               \
            _Pragma("unroll")                                                            \
            for (int i = 0; i < 4; i++) {                                                \
                _Pragma("unroll")                                                        \
                for (int t = 0; t < 4; t++)                                              \
                    lsP[w][PSET][(hi * 4 + i) * 76 + t * 16 + la] = (bf16)S[t][i];       \
            }                                                                            \
        }
        SM_SET(sA, mA, ofA, lfA, 0)
        SM_SET(sB, mB, ofB, lfB, 1)
        #undef SM_SET

        bf16x8 pA0 = *(bf16x8*)&lsP[w][0][la * 76 + hi * 8];
        bf16x8 pA1 = *(bf16x8*)&lsP[w][0][la * 76 + 32 + hi * 8];
        bf16x8 pB0 = *(bf16x8*)&lsP[w][1][la * 76 + hi * 8];
        bf16x8 pB1 = *(bf16x8*)&lsP[w][1][la * 76 + 32 + hi * 8];
        #pragma unroll
        for (int t = 0; t < 4; t++) {
            bf16x8 vf0 = *(bf16x8*)&lsVT[(t * 16 + la) * 68 + hi * 8];
            bf16x8 vf1 = *(bf16x8*)&lsVT[(t * 16 + la) * 68 + 32 + hi * 8];
            ofA[t] = mfma16(pA0, vf0, ofA[t]);
            ofA[t] = mfma16(pA1, vf1, ofA[t]);
            ofB[t] = mfma16(pB0, vf0, ofB[t]);
            ofB[t] = mfma16(pB1, vf1, ofB[t]);
        }
        lfA = mfma16(pA0, ones, lfA);
        lfA = mfma16(pA1, ones, lfA);
        lfB = mfma16(pB0, ones, lfB);
        lfB = mfma16(pB1, ones, lfB);
        __syncthreads();
    }
    float invA[4], invB[4];
    #pragma unroll
    for (int i = 0; i < 4; i++) { invA[i] = 1.f / lfA[i]; invB[i] = 1.f / lfB[i]; }
    #pragma unroll
    for (int t = 0; t < 4; t++) {
        #pragma unroll
        for (int i = 0; i < 4; i++) {
            long rowA = (long)b * NN + qr0 + hi * 4 + i;
            o[rowA * CC + h * 64 + t * 16 + la]        = (bf16)(ofA[t][i] * invA[i]);
            o[(rowA + 64) * CC + h * 64 + t * 16 + la] = (bf16)(ofB[t][i] * invB[i]);
        }
    }
}

extern "C" void kernel_launch(void* const* d_in, const int* in_sizes, int n_in,
                              void* d_out, int out_size, void* d_ws, size_t ws_size,
                              hipStream_t stream)
{
    const float* x     = (const float*)d_in[0];
    const int*   rpi   = (const int*)d_in[2];
    const float* Wqkv  = (const float*)d_in[3];
    const float* Wproj = (const float*)d_in[4];
    const float* bproj = (const float*)d_in[5];
    const float* rtab  = (const float*)d_in[6];
    const float* ln1g  = (const float*)d_in[7];
    const float* ln1b  = (const float*)d_in[8];
    const float* g1    = (const float*)d_in[9];
    const float* g2    = (const float*)d_in[10];
    const float* ln2tg = (const float*)d_in[11];
    const float* ln2tb = (const float*)d_in[12];
    const float* f1tW  = (const float*)d_in[13];
    const float* f1tb  = (const float*)d_in[14];
    const float* f2tW  = (const float*)d_in[15];
    const float* f2tb  = (const float*)d_in[16];
    const float* ln2fg = (const float*)d_in[17];
    const float* ln2fb = (const float*)d_in[18];
    const float* f1fW  = (const float*)d_in[19];
    const float* f1fb  = (const float*)d_in[20];
    const float* f2fW  = (const float*)d_in[21];
    const float* f2fb  = (const float*)d_in[22];
    float* out = (float*)d_out;

    // ws: 4 regions x 12.58MB bf16 = 50.33MB.
    //  rA: q  -> Wproj(bf16) -> h2        rB: k -> hg lo     rC: v -> hg hi
    //  rD: Wqkv(bf16) -> o -> MLP weight pairs (w1,w2 bf16)
    // d_out: h (bf16 LN1) -> bias table (bf16) -> x1 (fp32 residual/result)
    char* ws = (char*)d_ws;
    const long TOKC = (long)BB * NN * CC;        // 6291456
    const int  NFC  = HID * CC;                  // 2359296
    bf16* rA = (bf16*)ws;
    bf16* rB = rA + TOKC;
    bf16* rC = rB + TOKC;
    bf16* rD = rC + TOKC;

    bf16 *qb = rA, *kb = rB, *vb = rC, *o = rD;
    bf16  *h    = (bf16*)d_out;
    bf16  *bbt  = (bf16*)d_out;
    float *x1   = out;
    bf16  *wqkv = rD;     // before o
    bf16  *wpro = rA;     // after q dies
    bf16  *h2   = rA;     // after Wproj dies
    bf16  *hg   = rB;     // spans rB+rC
    bf16  *w1   = rD;     // after o dies
    bf16  *w2   = rD + NFC;

    // 1. LN1 (fp32 x -> bf16 h) fused with Wqkv cast (rD; o not yet written)
    ln1_cast_kernel<<<2048 + 1728, 256, 0, stream>>>(x, h, ln1g, ln1b, Wqkv, wqkv);
    // 2. QKV projection
    {
        dim3 g(2304 / 128, 8192 / 128, 1);
        gemm_bt<MODE_QKV, 768, 768, 128, 128, 3><<<g, 256, 0, stream>>>(h, wqkv, nullptr, nullptr, nullptr, qb, kb, vb, nullptr, 0);
    }
    // 3. bias table in fragment layout (h dead)
    bias_kernel<<<768, 256, 0, stream>>>(rpi, rtab, bbt);
    // 4. attention (reads rA,rB,rC,bbt; writes o=rD; wqkv dead)
    attn_kernel<<<BB * 4 * HH, 256, 0, stream>>>(qb, kb, vb, bbt, o);
    // 5a. cast Wproj -> bf16 (rA; q dead)
    cast2_kernel<<<576, 256, 0, stream>>>(Wproj, 147456, nullptr, wpro);
    // 5b. proj + residual -> x1 (overwrites d_out; bbt dead); 64x128 tile -> 768 blocks (3/CU)
    {
        dim3 g(768 / 128, 8192 / 64, 1);
        gemm_bt<MODE_PROJ, 768, 768, 64, 128, 4><<<g, 256, 0, stream>>>(o, wpro, bproj, x, g1, nullptr, nullptr, nullptr, x1, 0);
    }
    // 6. LN2 both halves -> h2 (rA; Wproj dead), x1 += g2*fc2_bias; fused t-weight cast (rD; o dead)
    ln2_cast_kernel<<<2048 + 4608, 256, 0, stream>>>(x1, h2, ln2tg, ln2tb, ln2fg, ln2fb, g2, f2tb, f2fb,
                                                     f1tW, f2tW, w1);
    // 7. MLP t-half: GELU, OUT split-K=2 with 64x128 tile (3/CU)
    {
        dim3 ga(3072 / 128, 4096 / 128, 1);
        gemm_bt<MODE_GELU, 768, 768, 128, 128, 3><<<ga, 256, 0, stream>>>(h2, w1, f1tb, nullptr, nullptr, hg, nullptr, nullptr, nullptr, 0);
        dim3 gb(768 / 128, 4096 / 64, 2);
        gemm_bt<MODE_OUT, 3072, 1536, 64, 128, 4><<<gb, 256, 0, stream>>>(hg, w2, nullptr, nullptr, g2, nullptr, nullptr, nullptr, out, 0);
    }
    // 8. MLP f-half
    cast2_kernel<<<4608, 256, 0, stream>>>(f1fW, NFC / 4, f2fW, w1);
    {
        dim3 ga(3072 / 128, 4096 / 128, 1);
        gemm_bt<MODE_GELU, 768, 768, 128, 128, 3><<<ga, 256, 0, stream>>>(h2 + (long)4096 * CC, w1, f1fb, nullptr, nullptr, hg, nullptr, nullptr, nullptr, 0);
        dim3 gb(768 / 128, 4096 / 64, 2);
        gemm_bt<MODE_OUT, 3072, 1536, 64, 128, 4><<<gb, 256, 0, stream>>>(hg, w2, nullptr, nullptr, g2, nullptr, nullptr, nullptr, out, 256);
    }
}